// Round 1
// baseline (2718.632 us; speedup 1.0000x reference)
//
#include <hip/hip_runtime.h>
#include <math.h>

#define N_NODES  500000
#define N_EDGES  8000000
#define N_GRAPHS 25000
#define SD  119   // 20+27+36+36 concatenated segment-sum dim
#define RD  175
#define H1  96
#define H2  63
#define NT  138
#define GPB 16    // graphs per block in dense kernels
#define SCAN_CHUNK 2048
#define NB_SCAN 245   // ceil(500000/2048)

static __device__ __forceinline__ float selu_f(float m){
    const float scale=1.0507009873554805f, alpha=1.6732632423543772f;
    return m > 0.0f ? scale*m : scale*alpha*(__expf(m)-1.0f);
}

// ---------------- init ----------------
__global__ void k_init(int* hist, int* gstart, int* gend){
    int i = blockIdx.x*256 + threadIdx.x;
    if(i <= N_NODES) hist[i] = 0;
    if(i <  N_GRAPHS){ gstart[i]=0; gend[i]=0; }
}

// ---------------- CSR build ----------------
__global__ void k_hist(const int* __restrict__ dst, int* __restrict__ hist){
    int e = blockIdx.x*256 + threadIdx.x;
    if(e < N_EDGES) atomicAdd(&hist[dst[e]], 1);
}

__device__ __forceinline__ int block_excl_scan_256(int v){
    __shared__ int sh[256];
    int t = threadIdx.x;
    sh[t] = v; __syncthreads();
    int acc = v;
    for(int off=1; off<256; off<<=1){
        int add = (t>=off) ? sh[t-off] : 0;
        __syncthreads();
        acc += add;
        sh[t] = acc;
        __syncthreads();
    }
    return acc - v;
}

__global__ void k_scan1(const int* __restrict__ hist, int* __restrict__ partials){
    int base = blockIdx.x*SCAN_CHUNK;
    int s = 0;
    for(int i=threadIdx.x; i<SCAN_CHUNK; i+=256){
        int idx = base+i;
        if(idx < N_NODES) s += hist[idx];
    }
    // block reduce
    __shared__ int sh[256];
    sh[threadIdx.x]=s; __syncthreads();
    for(int off=128; off>0; off>>=1){
        if(threadIdx.x<off) sh[threadIdx.x]+=sh[threadIdx.x+off];
        __syncthreads();
    }
    if(threadIdx.x==0) partials[blockIdx.x]=sh[0];
}

__global__ void k_scan2(int* partials){
    int t = threadIdx.x;
    int v = (t<NB_SCAN) ? partials[t] : 0;
    int exc = block_excl_scan_256(v);
    if(t<NB_SCAN) partials[t]=exc;
}

__global__ void k_scan3(const int* __restrict__ hist, const int* __restrict__ partials,
                        int* __restrict__ row_ptr, int* __restrict__ cursor){
    int base = blockIdx.x*SCAN_CHUNK;
    int t = threadIdx.x;
    int local[8]; int s=0;
    #pragma unroll
    for(int i=0;i<8;i++){
        int idx = base + t*8 + i;
        int v = (idx<N_NODES) ? hist[idx] : 0;
        local[i]=s; s+=v;
    }
    int texc = block_excl_scan_256(s) + partials[blockIdx.x];
    #pragma unroll
    for(int i=0;i<8;i++){
        int idx = base + t*8 + i;
        if(idx<N_NODES){ int v=texc+local[i]; row_ptr[idx]=v; cursor[idx]=v; }
    }
    if(blockIdx.x==0 && t==0) row_ptr[N_NODES]=N_EDGES;
}

__global__ void k_scatter(const int* __restrict__ src, const int* __restrict__ dst,
                          int* __restrict__ cursor, int* __restrict__ csr){
    int e = blockIdx.x*256 + threadIdx.x;
    if(e < N_EDGES){
        int pos = atomicAdd(&cursor[dst[e]], 1);
        csr[pos] = src[e];
    }
}

// ---------------- graph boundaries (batch is sorted) ----------------
__global__ void k_bounds(const int* __restrict__ batch, int* __restrict__ gstart, int* __restrict__ gend){
    int n = blockIdx.x*256 + threadIdx.x;
    if(n >= N_NODES) return;
    int b = batch[n];
    if(n==0        || batch[n-1]!=b) gstart[b]=n;
    if(n==N_NODES-1|| batch[n+1]!=b) gend[b]=n+1;
}

// ---------------- node transform: y = x @ W + b ----------------
template<int DIN,int DOUT>
__global__ __launch_bounds__(256) void k_transform(const float* __restrict__ x, const float* __restrict__ W,
                                                   const float* __restrict__ bias, float* __restrict__ y){
    __shared__ float sw[DIN*DOUT];
    __shared__ float sb[DOUT];
    int t = threadIdx.x;
    for(int i=t;i<DIN*DOUT;i+=256) sw[i]=W[i];
    if(t<DOUT) sb[t]=bias[t];
    __syncthreads();
    int gid = blockIdx.x*256 + t;
    if(gid >= N_NODES*DOUT) return;
    int n = gid/DOUT, o = gid - n*DOUT;
    const float* xr = x + (size_t)n*DIN;
    float acc = sb[o];
    #pragma unroll
    for(int i=0;i<DIN;i++) acc = fmaf(xr[i], sw[i*DOUT+o], acc);
    y[gid]=acc;
}

// ---------------- aggregate: x_out[n][f] = selu(finite(max over in-edges of y[src][f])) ----------------
template<int D>
__global__ __launch_bounds__(256) void k_agg(const float* __restrict__ y, const int* __restrict__ row_ptr,
                                             const int* __restrict__ csr, float* __restrict__ xo){
    int gid = blockIdx.x*256 + threadIdx.x;
    if(gid >= N_NODES*D) return;
    int n = gid/D, f = gid - n*D;
    int beg = row_ptr[n], end = row_ptr[n+1];
    float m = -INFINITY;
    int j = beg;
    for(; j+4<=end; j+=4){
        int s0=csr[j], s1=csr[j+1], s2=csr[j+2], s3=csr[j+3];
        float v0=y[s0*D+f], v1=y[s1*D+f], v2=y[s2*D+f], v3=y[s3*D+f];
        m = fmaxf(m, fmaxf(fmaxf(v0,v1), fmaxf(v2,v3)));
    }
    for(; j<end; j++) m = fmaxf(m, y[csr[j]*D+f]);
    if(!isfinite(m)) m = 0.0f;   // empty segment -> 0 (PyG semantics)
    xo[gid] = selu_f(m);
}

// ---------------- per-graph segment sum into S[:, off:off+D] ----------------
template<int D>
__global__ void k_segsum(const float* __restrict__ x, const int* __restrict__ gs, const int* __restrict__ ge,
                         float* __restrict__ S, int off){
    int g = blockIdx.x; int f = threadIdx.x;
    if(f >= D) return;
    int b = gs[g], e = ge[g];
    float acc = 0.f;
    for(int n=b;n<e;n++) acc += x[(size_t)n*D+f];
    S[(size_t)g*SD + off + f] = acc;
}

// ---------------- readout: r = S @ Wcat + sum(b) ----------------
__global__ __launch_bounds__(192) void k_readout(const float* __restrict__ S,
    const float* __restrict__ w1,const float* __restrict__ b1,
    const float* __restrict__ w2,const float* __restrict__ b2,
    const float* __restrict__ w3,const float* __restrict__ b3,
    const float* __restrict__ w4,const float* __restrict__ b4,
    float* __restrict__ r){
    __shared__ float sH[GPB][SD];
    int t = threadIdx.x;
    int g0 = blockIdx.x*GPB;
    for(int i=t;i<GPB*SD;i+=192){
        int gl=i/SD, k=i-gl*SD;
        int g=g0+gl;
        sH[gl][k] = (g<N_GRAPHS) ? S[(size_t)g*SD+k] : 0.f;
    }
    __syncthreads();
    int j = t;
    if(j < RD){
        float acc[GPB];
        float bj = b1[j]+b2[j]+b3[j]+b4[j];
        #pragma unroll
        for(int gl=0;gl<GPB;gl++) acc[gl]=bj;
        for(int k=0;k<20;k++){ float wv=w1[k*RD+j];
            #pragma unroll
            for(int gl=0;gl<GPB;gl++) acc[gl] += sH[gl][k]*wv; }
        for(int k=0;k<27;k++){ float wv=w2[k*RD+j];
            #pragma unroll
            for(int gl=0;gl<GPB;gl++) acc[gl] += sH[gl][20+k]*wv; }
        for(int k=0;k<36;k++){ float wv=w3[k*RD+j];
            #pragma unroll
            for(int gl=0;gl<GPB;gl++) acc[gl] += sH[gl][47+k]*wv; }
        for(int k=0;k<36;k++){ float wv=w4[k*RD+j];
            #pragma unroll
            for(int gl=0;gl<GPB;gl++) acc[gl] += sH[gl][83+k]*wv; }
        int ng = min(GPB, N_GRAPHS-g0);
        for(int gl=0;gl<ng;gl++) r[(size_t)(g0+gl)*RD+j] = acc[gl];
    }
}

// ---------------- fc1: z1 = [r, mol] @ w + b, + BN partial stats ----------------
__global__ __launch_bounds__(128) void k_fc1(const float* __restrict__ r, const float* __restrict__ mol,
    const float* __restrict__ w, const float* __restrict__ b,
    float* __restrict__ z1, float* __restrict__ ps, float* __restrict__ pq){
    __shared__ float sH[GPB][RD+10];
    int t = threadIdx.x;
    int g0 = blockIdx.x*GPB;
    for(int i=t;i<GPB*(RD+10);i+=128){
        int gl=i/(RD+10), k=i-gl*(RD+10);
        int g=g0+gl;
        float v=0.f;
        if(g<N_GRAPHS) v = (k<RD) ? r[(size_t)g*RD+k] : mol[(size_t)g*10 + (k-RD)];
        sH[gl][k]=v;
    }
    __syncthreads();
    int j = t;
    if(j < H1){
        float acc[GPB]; float bj=b[j];
        #pragma unroll
        for(int gl=0;gl<GPB;gl++) acc[gl]=bj;
        for(int k=0;k<RD+10;k++){
            float wv = w[k*H1+j];
            #pragma unroll
            for(int gl=0;gl<GPB;gl++) acc[gl] += sH[gl][k]*wv;
        }
        int ng = min(GPB, N_GRAPHS-g0);
        float psum=0.f, psq=0.f;
        for(int gl=0;gl<ng;gl++){
            z1[(size_t)(g0+gl)*H1+j]=acc[gl];
            psum+=acc[gl]; psq+=acc[gl]*acc[gl];
        }
        ps[blockIdx.x*H1+j]=psum;
        pq[blockIdx.x*H1+j]=psq;
    }
}

// ---------------- BN finalize: a = g/sqrt(var+eps), c = b - a*mu ----------------
__global__ __launch_bounds__(256) void k_bnfin(const float* __restrict__ ps, const float* __restrict__ pq,
    int nb, int H, const float* __restrict__ gamma, const float* __restrict__ beta,
    float* __restrict__ a, float* __restrict__ c){
    int j = blockIdx.x;
    int t = threadIdx.x;
    float s=0.f, q=0.f;
    for(int i=t;i<nb;i+=256){ s+=ps[(size_t)i*H+j]; q+=pq[(size_t)i*H+j]; }
    __shared__ float sh1[256], sh2[256];
    sh1[t]=s; sh2[t]=q; __syncthreads();
    for(int off=128;off>0;off>>=1){
        if(t<off){ sh1[t]+=sh1[t+off]; sh2[t]+=sh2[t+off]; }
        __syncthreads();
    }
    if(t==0){
        float mean = sh1[0]/(float)N_GRAPHS;
        float var  = sh2[0]/(float)N_GRAPHS - mean*mean;
        float inv  = 1.0f/sqrtf(var + 1e-5f);
        float aj = gamma[j]*inv;
        a[j]=aj; c[j]=beta[j]-aj*mean;
    }
}

// ---------------- fc2: z2 = relu(bn1(z1)) @ w + b, + BN partial stats ----------------
__global__ __launch_bounds__(64) void k_fc2(const float* __restrict__ z1, const float* __restrict__ a1,
    const float* __restrict__ c1, const float* __restrict__ w, const float* __restrict__ b,
    float* __restrict__ z2, float* __restrict__ ps, float* __restrict__ pq){
    __shared__ float sH[GPB][H1];
    int t = threadIdx.x;
    int g0 = blockIdx.x*GPB;
    for(int i=t;i<GPB*H1;i+=64){
        int gl=i/H1, k=i-gl*H1;
        int g=g0+gl;
        float v=0.f;
        if(g<N_GRAPHS){ float z=z1[(size_t)g*H1+k]; v=fmaxf(a1[k]*z+c1[k],0.f); }
        sH[gl][k]=v;
    }
    __syncthreads();
    int j = t;
    if(j < H2){
        float acc[GPB]; float bj=b[j];
        #pragma unroll
        for(int gl=0;gl<GPB;gl++) acc[gl]=bj;
        for(int k=0;k<H1;k++){
            float wv=w[k*H2+j];
            #pragma unroll
            for(int gl=0;gl<GPB;gl++) acc[gl]+=sH[gl][k]*wv;
        }
        int ng=min(GPB,N_GRAPHS-g0);
        float psum=0.f,psq=0.f;
        for(int gl=0;gl<ng;gl++){
            z2[(size_t)(g0+gl)*H2+j]=acc[gl];
            psum+=acc[gl]; psq+=acc[gl]*acc[gl];
        }
        ps[blockIdx.x*H2+j]=psum; pq[blockIdx.x*H2+j]=psq;
    }
}

// ---------------- out: sigmoid(relu(bn2(z2)) @ w + b) ----------------
__global__ __launch_bounds__(192) void k_out(const float* __restrict__ z2, const float* __restrict__ a2,
    const float* __restrict__ c2, const float* __restrict__ w, const float* __restrict__ b,
    float* __restrict__ out){
    __shared__ float sH[GPB][H2];
    int t = threadIdx.x;
    int g0 = blockIdx.x*GPB;
    for(int i=t;i<GPB*H2;i+=192){
        int gl=i/H2, k=i-gl*H2;
        int g=g0+gl;
        float v=0.f;
        if(g<N_GRAPHS){ float z=z2[(size_t)g*H2+k]; v=fmaxf(a2[k]*z+c2[k],0.f); }
        sH[gl][k]=v;
    }
    __syncthreads();
    int j = t;
    if(j < NT){
        float acc[GPB]; float bj=b[j];
        #pragma unroll
        for(int gl=0;gl<GPB;gl++) acc[gl]=bj;
        for(int k=0;k<H2;k++){
            float wv=w[k*NT+j];
            #pragma unroll
            for(int gl=0;gl<GPB;gl++) acc[gl]+=sH[gl][k]*wv;
        }
        int ng=min(GPB,N_GRAPHS-g0);
        for(int gl=0;gl<ng;gl++)
            out[(size_t)(g0+gl)*NT+j] = 1.0f/(1.0f+__expf(-acc[gl]));
    }
}

// ---------------- launcher ----------------
static inline int ceil_div(int a,int b){ return (a+b-1)/b; }

extern "C" void kernel_launch(void* const* d_in, const int* in_sizes, int n_in,
                              void* d_out, int out_size, void* d_ws, size_t ws_size,
                              hipStream_t stream) {
    const float* x     = (const float*)d_in[0];
    const float* mol   = (const float*)d_in[1];
    const int*   ei    = (const int*)  d_in[2];   // [0:E]=src, [E:2E]=dst
    const int*   batch = (const int*)  d_in[3];
    const float* w_g1=(const float*)d_in[4];  const float* b_g1=(const float*)d_in[5];
    const float* w_g2=(const float*)d_in[6];  const float* b_g2=(const float*)d_in[7];
    const float* w_g3=(const float*)d_in[8];  const float* b_g3=(const float*)d_in[9];
    const float* w_g4=(const float*)d_in[10]; const float* b_g4=(const float*)d_in[11];
    const float* w_r1=(const float*)d_in[12]; const float* b_r1=(const float*)d_in[13];
    const float* w_r2=(const float*)d_in[14]; const float* b_r2=(const float*)d_in[15];
    const float* w_r3=(const float*)d_in[16]; const float* b_r3=(const float*)d_in[17];
    const float* w_r4=(const float*)d_in[18]; const float* b_r4=(const float*)d_in[19];
    const float* w_fc1=(const float*)d_in[20]; const float* b_fc1=(const float*)d_in[21];
    const float* bn1_g=(const float*)d_in[22]; const float* bn1_b=(const float*)d_in[23];
    const float* w_fc2=(const float*)d_in[24]; const float* b_fc2=(const float*)d_in[25];
    const float* bn2_g=(const float*)d_in[26]; const float* bn2_b=(const float*)d_in[27];
    const float* w_out=(const float*)d_in[28]; const float* b_out=(const float*)d_in[29];
    float* out = (float*)d_out;

    // workspace carve-up (256B aligned regions)
    char* p = (char*)d_ws;
    auto take=[&](size_t bytes)->char*{ char* q=p; p += (bytes+255)&~(size_t)255; return q; };
    float* y   = (float*)take((size_t)N_NODES*36*4);
    float* xa  = (float*)take((size_t)N_NODES*36*4);
    float* xb  = (float*)take((size_t)N_NODES*36*4);
    int* hist    = (int*)take((size_t)(N_NODES+1)*4);
    int* row_ptr = (int*)take((size_t)(N_NODES+1)*4);
    int* cursor  = (int*)take((size_t)N_NODES*4);
    int* partials= (int*)take(256*4);
    int* csr     = (int*)take((size_t)N_EDGES*4);
    int* gstart  = (int*)take((size_t)N_GRAPHS*4);
    int* gend    = (int*)take((size_t)N_GRAPHS*4);
    float* S  = (float*)take((size_t)N_GRAPHS*SD*4);
    float* r  = (float*)take((size_t)N_GRAPHS*RD*4);
    float* z1 = (float*)take((size_t)N_GRAPHS*H1*4);
    float* z2 = (float*)take((size_t)N_GRAPHS*H2*4);
    const int NB_G = ceil_div(N_GRAPHS, GPB);   // 1563
    float* p1s=(float*)take((size_t)NB_G*H1*4);
    float* p1q=(float*)take((size_t)NB_G*H1*4);
    float* p2s=(float*)take((size_t)NB_G*H2*4);
    float* p2q=(float*)take((size_t)NB_G*H2*4);
    float* a1=(float*)take(H1*4); float* c1=(float*)take(H1*4);
    float* a2=(float*)take(H2*4); float* c2=(float*)take(H2*4);

    const int* src = ei;
    const int* dst = ei + N_EDGES;

    k_init<<<ceil_div(N_NODES+1,256),256,0,stream>>>(hist,gstart,gend);
    k_hist<<<ceil_div(N_EDGES,256),256,0,stream>>>(dst,hist);
    k_scan1<<<NB_SCAN,256,0,stream>>>(hist,partials);
    k_scan2<<<1,256,0,stream>>>(partials);
    k_scan3<<<NB_SCAN,256,0,stream>>>(hist,partials,row_ptr,cursor);
    k_scatter<<<ceil_div(N_EDGES,256),256,0,stream>>>(src,dst,cursor,csr);
    k_bounds<<<ceil_div(N_NODES,256),256,0,stream>>>(batch,gstart,gend);

    // layer 1: x(48) -> y(20) -> xa(20)
    k_transform<48,20><<<ceil_div(N_NODES*20,256),256,0,stream>>>(x,w_g1,b_g1,y);
    k_agg<20><<<ceil_div(N_NODES*20,256),256,0,stream>>>(y,row_ptr,csr,xa);
    k_segsum<20><<<N_GRAPHS,64,0,stream>>>(xa,gstart,gend,S,0);
    // layer 2: xa(20) -> y(27) -> xb(27)
    k_transform<20,27><<<ceil_div(N_NODES*27,256),256,0,stream>>>(xa,w_g2,b_g2,y);
    k_agg<27><<<ceil_div(N_NODES*27,256),256,0,stream>>>(y,row_ptr,csr,xb);
    k_segsum<27><<<N_GRAPHS,64,0,stream>>>(xb,gstart,gend,S,20);
    // layer 3: xb(27) -> y(36) -> xa(36)
    k_transform<27,36><<<ceil_div(N_NODES*36,256),256,0,stream>>>(xb,w_g3,b_g3,y);
    k_agg<36><<<ceil_div(N_NODES*36,256),256,0,stream>>>(y,row_ptr,csr,xa);
    k_segsum<36><<<N_GRAPHS,64,0,stream>>>(xa,gstart,gend,S,47);
    // layer 4: xa(36) -> y(36) -> xb(36)
    k_transform<36,36><<<ceil_div(N_NODES*36,256),256,0,stream>>>(xa,w_g4,b_g4,y);
    k_agg<36><<<ceil_div(N_NODES*36,256),256,0,stream>>>(y,row_ptr,csr,xb);
    k_segsum<36><<<N_GRAPHS,64,0,stream>>>(xb,gstart,gend,S,83);

    k_readout<<<NB_G,192,0,stream>>>(S,w_r1,b_r1,w_r2,b_r2,w_r3,b_r3,w_r4,b_r4,r);
    k_fc1<<<NB_G,128,0,stream>>>(r,mol,w_fc1,b_fc1,z1,p1s,p1q);
    k_bnfin<<<H1,256,0,stream>>>(p1s,p1q,NB_G,H1,bn1_g,bn1_b,a1,c1);
    k_fc2<<<NB_G,64,0,stream>>>(z1,a1,c1,w_fc2,b_fc2,z2,p2s,p2q);
    k_bnfin<<<H2,256,0,stream>>>(p2s,p2q,NB_G,H2,bn2_g,bn2_b,a2,c2);
    k_out<<<NB_G,192,0,stream>>>(z2,a2,c2,w_out,b_out,out);
}